// Round 10
// baseline (170.641 us; speedup 1.0000x reference)
//
#include <hip/hip_runtime.h>
#include <hip/hip_bf16.h>
#include <cstdint>

#define B_ 4
#define C_ 256
#define N_ 4096
#define D_ 32
#define LOG2E 1.44269504088896f

typedef __attribute__((ext_vector_type(8))) short bf16x8;
typedef __attribute__((ext_vector_type(4))) short s16x4;
typedef __attribute__((ext_vector_type(4))) float f32x4;
typedef __attribute__((ext_vector_type(4))) int i32x4;

__device__ inline unsigned short f2bf(float f) {
    union { float f; uint32_t u; } v; v.f = f;
    uint32_t u = v.u;
    u += 0x7FFFu + ((u >> 16) & 1u);   // round-to-nearest-even
    return (unsigned short)(u >> 16);
}

__device__ inline float exp2_raw(float x) {
    float r;
    asm("v_exp_f32 %0, %1" : "=v"(r) : "v"(x));
    return r;
}

// ---------------------------------------------------------------------------
// One-time weight conversion: Wb[320][256] bf16 (rows 0-31 Wq, 32-63 Wk,
// 64-319 Wv). 80 blocks x 256 thr x 4 elems.
// ---------------------------------------------------------------------------
__global__ __launch_bounds__(256) void wconv_kernel(
    const float* __restrict__ Wq, const float* __restrict__ Wk,
    const float* __restrict__ Wv, unsigned short* __restrict__ Wb)
{
    int i = (blockIdx.x * 256 + threadIdx.x) * 4;   // < 81920
    int r = i >> 8, k = i & 255;
    const float* src = (r < 32) ? Wq + r * 256 + k
                     : (r < 64) ? Wk + (r - 32) * 256 + k
                                : Wv + (r - 64) * 256 + k;
    f32x4 v = *reinterpret_cast<const f32x4*>(src);
    s16x4 o;
    #pragma unroll
    for (int j = 0; j < 4; ++j) o[j] = (short)f2bf(v[j]);
    *reinterpret_cast<s16x4*>(Wb + i) = o;
}

// ---------------------------------------------------------------------------
// Projection v4b: [320 x 256] bf16 W (global/L2) x x-tile of 32 n.
// grid (128, B), 256 thr = 4 waves, wave w rows w*80..+79.
// Change vs v4: Afn prefetch is UNCONDITIONAL (kcn wraps) so the compiler can
// use counted vmcnt instead of draining in a conditional region.
// Q rows are scaled by LOG2E so attn can use raw v_exp_f32 (2^x).
// ---------------------------------------------------------------------------
__global__ __launch_bounds__(256) void proj_kernel(
    const float* __restrict__ x, const unsigned short* __restrict__ Wb,
    const float* __restrict__ bq, const float* __restrict__ bk,
    const float* __restrict__ bv,
    unsigned short* __restrict__ Qt, unsigned short* __restrict__ Kt,
    unsigned short* __restrict__ V)
{
    __shared__ __align__(16) char smem[16384];   // x_lds [32 n][512 B]
    const int t  = threadIdx.x;
    const int w  = t >> 6;
    const int l  = t & 63;
    const int lg = l >> 4;
    const int ll = l & 15;
    const int n0 = blockIdx.x * 32;
    const int b  = blockIdx.y;

    // ---- stage x [256 k][32 n] fp32 -> x_lds [n][k] bf16, swizzled ----
    #pragma unroll
    for (int rep = 0; rep < 8; ++rep) {
        int flat = rep * 256 + t;
        int c = flat >> 3, chunk = flat & 7;
        f32x4 xv = *reinterpret_cast<const f32x4*>(
            x + ((size_t)(b * C_ + c)) * N_ + n0 + chunk * 4);
        #pragma unroll
        for (int j = 0; j < 4; ++j) {
            int n = chunk * 4 + j;
            *reinterpret_cast<unsigned short*>(
                smem + n * 512 + ((c * 2) ^ ((n & 7) << 4))) = f2bf(xv[j]);
        }
    }

    // ---- A-frag prologue (kc=0) from global bf16 W ----
    bf16x8 Af[5], Afn[5];
    #pragma unroll
    for (int rt = 0; rt < 5; ++rt) {
        int r = w * 80 + rt * 16 + ll;
        Af[rt] = *reinterpret_cast<const bf16x8*>(Wb + r * 256 + lg * 8);
    }

    f32x4 acc[5][2];
    #pragma unroll
    for (int rt = 0; rt < 5; ++rt)
        #pragma unroll
        for (int nt = 0; nt < 2; ++nt) acc[rt][nt] = (f32x4){0.f, 0.f, 0.f, 0.f};

    __syncthreads();   // x_lds ready

    for (int kc = 0; kc < 8; ++kc) {
        const int kcn = (kc + 1) & 7;   // unconditional prefetch (wraps)
        #pragma unroll
        for (int rt = 0; rt < 5; ++rt) {
            int r = w * 80 + rt * 16 + ll;
            Afn[rt] = *reinterpret_cast<const bf16x8*>(
                Wb + r * 256 + kcn * 32 + lg * 8);
        }
        bf16x8 Bf[2];
        #pragma unroll
        for (int nt = 0; nt < 2; ++nt) {
            int n = nt * 16 + ll;
            Bf[nt] = *reinterpret_cast<const bf16x8*>(
                smem + n * 512 + ((kc * 64 + lg * 16) ^ ((n & 7) << 4)));
        }
        #pragma unroll
        for (int rt = 0; rt < 5; ++rt)
            #pragma unroll
            for (int nt = 0; nt < 2; ++nt)
                acc[rt][nt] = __builtin_amdgcn_mfma_f32_16x16x32_bf16(
                    Af[rt], Bf[nt], acc[rt][nt], 0, 0, 0);
        #pragma unroll
        for (int rt = 0; rt < 5; ++rt) Af[rt] = Afn[rt];
    }

    // ---- epilogue: bias (+LOG2E scale for Q rows) + store ----
    #pragma unroll
    for (int rt = 0; rt < 5; ++rt) {
        const int rrow = w * 80 + rt * 16 + lg * 4;   // + q (0..3)
        float bias[4];
        #pragma unroll
        for (int q = 0; q < 4; ++q) {
            int rg = rrow + q;
            bias[q] = (rg < 32) ? bq[rg] : (rg < 64) ? bk[rg - 32] : bv[rg - 64];
        }
        if (rrow < 64) {
            const int d0 = rrow & 31;
            const bool isQ = (rrow < 32);
            unsigned short* dst = isQ ? Qt : Kt;
            #pragma unroll
            for (int nt = 0; nt < 2; ++nt) {
                int n = n0 + nt * 16 + ll;
                s16x4 sv;
                #pragma unroll
                for (int q = 0; q < 4; ++q) {
                    float v = acc[rt][nt][q] + bias[q];
                    if (isQ) v *= LOG2E;
                    sv[q] = (short)f2bf(v);
                }
                *reinterpret_cast<s16x4*>(dst + ((size_t)b * N_ + n) * D_ + d0) = sv;
            }
        } else {
            #pragma unroll
            for (int nt = 0; nt < 2; ++nt) {
                int n = n0 + nt * 16 + ll;
                #pragma unroll
                for (int q = 0; q < 4; ++q) {
                    int c = rrow - 64 + q;
                    V[((size_t)(b * C_ + c)) * N_ + n] = f2bf(acc[rt][nt][q] + bias[q]);
                }
            }
        }
    }
}

// ---------------------------------------------------------------------------
// Flash attention v6: query-split, single-buffered Vs with reg-staged V (T14),
// XCD-aware block swizzle (T1).
// grid 512 (1-D): id=(bid&7)*64+(bid>>3); b=id>>7; n0=(id&127)*32 -> each XCD
// works one batch-half (V[b] 2MB + K[b] 0.25MB fit its 4MB L2).
// 512 thr = 8 waves; LDS 40.5 KB -> 3 blocks/CU (24 waves/CU).
// Per tile: QK(1 MFMA)+exp+P-write | b1 | PV(8 MFMA) | b2 | ds_write V(t+1)
// from regs + issue V(t+2) loads. Vs race-free: writes after b2 (all readers
// passed), reads after b1 (lgkmcnt(0) before it publishes the writes).
// ---------------------------------------------------------------------------
__global__ __launch_bounds__(512) void attn_kernel(
    const unsigned short* __restrict__ Qt, const unsigned short* __restrict__ Kt,
    const unsigned short* __restrict__ Vg, const float* __restrict__ x,
    const float* __restrict__ gamma, float* __restrict__ out)
{
    // Vs 32KB @0 | P 2x4KB @32768 | Lbuf 128 f32 @40960
    __shared__ __align__(16) char smem[41472];
    char* Pbase = smem + 32768;
    float* LbufF = reinterpret_cast<float*>(smem + 40960);
    const int t  = threadIdx.x;
    const int w  = t >> 6;
    const int l  = t & 63;
    const int lg = l >> 4;
    const int ll = l & 15;
    const int qt_p = w >> 2;       // producer: q-tile (16 rows)
    const int jc   = w & 3;        // producer: j-tile within 64-key tile
    const int bid  = blockIdx.x;
    const int id   = (bid & 7) * 64 + (bid >> 3);   // XCD-contiguous remap
    const int b    = id >> 7;
    const int n0   = (id & 127) * 32;

    // ---- per-thread V staging geometry (4 chunks of 16B) ----
    const unsigned short* vsrc[4];
    int vdst[4];
    #pragma unroll
    for (int i = 0; i < 4; ++i) {
        int Lb  = i * 8192 + w * 1024 + l * 16;   // linear byte 0..32767
        int c   = Lb >> 7;                         // channel 0..255
        int off = Lb & 127;
        vsrc[i] = Vg + ((size_t)(b * C_ + c)) * N_ + (off >> 1);
        vdst[i] = c * 128 + (off ^ ((c & 7) << 4));
    }

    // producer Q fragment (constant over loop; pre-scaled by LOG2E)
    const bf16x8 qfrag = *reinterpret_cast<const bf16x8*>(
        Qt + ((size_t)b * N_ + n0 + qt_p * 16 + ll) * D_ + 8 * lg);

    f32x4 acc[2][2];
    #pragma unroll
    for (int qt = 0; qt < 2; ++qt)
        #pragma unroll
        for (int ct = 0; ct < 2; ++ct) acc[qt][ct] = (f32x4){0.f, 0.f, 0.f, 0.f};
    float l_lane[4] = {0.f, 0.f, 0.f, 0.f};

    // ---- prologue: V(0) -> Vs; issue V(1) loads; K(0) frag ----
    i32x4 vr[4];
    #pragma unroll
    for (int i = 0; i < 4; ++i) vr[i] = *reinterpret_cast<const i32x4*>(vsrc[i]);
    #pragma unroll
    for (int i = 0; i < 4; ++i) *reinterpret_cast<i32x4*>(smem + vdst[i]) = vr[i];
    #pragma unroll
    for (int i = 0; i < 4; ++i) vr[i] = *reinterpret_cast<const i32x4*>(vsrc[i] + 64);

    bf16x8 kcur = *reinterpret_cast<const bf16x8*>(
        Kt + ((size_t)b * N_ + jc * 16 + ll) * D_ + 8 * lg);

    asm volatile("s_waitcnt lgkmcnt(0)" ::: "memory");
    __builtin_amdgcn_s_barrier();
    asm volatile("" ::: "memory");

    const f32x4 zero4 = {0.f, 0.f, 0.f, 0.f};

    for (int kt = 0; kt < 64; ++kt) {
        const int pb  = kt & 1;
        const int ktn = (kt < 63) ? kt + 1 : 63;

        // ---- (a) prefetch next K frag; QK MFMA; exp2 ----
        bf16x8 knxt = *reinterpret_cast<const bf16x8*>(
            Kt + ((size_t)b * N_ + ktn * 64 + jc * 16 + ll) * D_ + 8 * lg);

        f32x4 sf = __builtin_amdgcn_mfma_f32_16x16x32_bf16(qfrag, kcur, zero4, 0, 0, 0);

        float pv[4];
        #pragma unroll
        for (int r = 0; r < 4; ++r) {
            float p = exp2_raw(fminf(sf[r], 86.f));
            pv[r] = p;
            l_lane[r] += p;
        }

        // ---- (b) write P (bf16, swizzled) ----
        char* Pw = Pbase + pb * 4096;
        #pragma unroll
        for (int r = 0; r < 4; ++r) {
            int row = qt_p * 16 + lg * 4 + r;
            int col = jc * 16 + ll;
            *reinterpret_cast<unsigned short*>(
                Pw + row * 128 + ((col * 2) ^ ((row & 7) << 4))) = f2bf(pv[r]);
        }

        // ---- barrier 1: P(t) + V(t) writes visible ----
        asm volatile("s_waitcnt lgkmcnt(0)" ::: "memory");
        __builtin_amdgcn_s_barrier();
        asm volatile("" ::: "memory");

        // ---- (d) PV on tile kt ----
        char* Pr = Pbase + pb * 4096;
        bf16x8 pfrag[2][2];
        #pragma unroll
        for (int qt = 0; qt < 2; ++qt)
            #pragma unroll
            for (int kh = 0; kh < 2; ++kh) {
                int row = qt * 16 + ll;
                pfrag[qt][kh] = *reinterpret_cast<const bf16x8*>(
                    Pr + row * 128 + ((kh * 64 + lg * 16) ^ ((row & 7) << 4)));
            }
        __builtin_amdgcn_s_setprio(1);
        #pragma unroll
        for (int ct = 0; ct < 2; ++ct) {
            int cl = w * 32 + ct * 16 + ll;   // channel 0..255
            #pragma unroll
            for (int kh = 0; kh < 2; ++kh) {
                bf16x8 vf = *reinterpret_cast<const bf16x8*>(
                    smem + cl * 128 + ((kh * 64 + lg * 16) ^ ((cl & 7) << 4)));
                #pragma unroll
                for (int qt = 0; qt < 2; ++qt)
                    acc[qt][ct] = __builtin_amdgcn_mfma_f32_16x16x32_bf16(
                        pfrag[qt][kh], vf, acc[qt][ct], 0, 0, 0);
            }
        }
        __builtin_amdgcn_s_setprio(0);

        // ---- barrier 2: all PV reads of Vs complete ----
        asm volatile("s_waitcnt lgkmcnt(0)" ::: "memory");
        __builtin_amdgcn_s_barrier();
        asm volatile("" ::: "memory");

        // ---- (f) write V(t+1) from regs; issue V(t+2) loads ----
        if (kt < 63) {
            #pragma unroll
            for (int i = 0; i < 4; ++i)
                *reinterpret_cast<i32x4*>(smem + vdst[i]) = vr[i];
            if (kt < 62) {
                #pragma unroll
                for (int i = 0; i < 4; ++i)
                    vr[i] = *reinterpret_cast<const i32x4*>(vsrc[i] + (kt + 2) * 64);
            }
        }

        kcur = knxt;
    }

    // ---- l: cross-lane reduce; combine the 4 jc-waves per q-tile ----
    #pragma unroll
    for (int off = 1; off < 16; off <<= 1)
        #pragma unroll
        for (int r = 0; r < 4; ++r)
            l_lane[r] += __shfl_xor(l_lane[r], off);
    if (ll == 0) {
        #pragma unroll
        for (int r = 0; r < 4; ++r) LbufF[w * 16 + lg * 4 + r] = l_lane[r];
    }
    __syncthreads();   // also drains remaining loads

    float inv[2][4];
    #pragma unroll
    for (int qt = 0; qt < 2; ++qt)
        #pragma unroll
        for (int r = 0; r < 4; ++r) {
            int lq = lg * 4 + r;
            float ls = LbufF[(qt * 4 + 0) * 16 + lq] + LbufF[(qt * 4 + 1) * 16 + lq]
                     + LbufF[(qt * 4 + 2) * 16 + lq] + LbufF[(qt * 4 + 3) * 16 + lq];
            inv[qt][r] = 1.f / ls;
        }

    // ---- epilogue: out = gamma*(acc*inv) + x, transpose via LDS ----
    #pragma unroll
    for (int qt = 0; qt < 2; ++qt)
        #pragma unroll
        for (int ct = 0; ct < 2; ++ct) {
            int cl = w * 32 + ct * 16 + ll;
            int ncol = qt * 16 + lg * 4;
            f32x4 v;
            #pragma unroll
            for (int r = 0; r < 4; ++r) v[r] = acc[qt][ct][r] * inv[qt][r];
            *reinterpret_cast<f32x4*>(smem + cl * 128 + ((ncol * 4) ^ ((cl & 7) << 4))) = v;
        }
    __syncthreads();

    const float g0 = gamma[0];
    #pragma unroll
    for (int p = 0; p < 4; ++p) {
        int li = p * 512 + t;       // < 2048 = 256 rows x 8 chunks
        int cl = li >> 3;           // 0..255
        int n4 = (li & 7) * 4;      // 0..28
        f32x4 ov = *reinterpret_cast<const f32x4*>(
            smem + cl * 128 + ((n4 * 4) ^ ((cl & 7) << 4)));
        size_t gi = ((size_t)(b * C_ + cl)) * N_ + n0 + n4;
        f32x4 xv = *reinterpret_cast<const f32x4*>(x + gi);
        f32x4 res;
        #pragma unroll
        for (int j = 0; j < 4; ++j) res[j] = g0 * ov[j] + xv[j];
        *reinterpret_cast<f32x4*>(out + gi) = res;
    }
}

extern "C" void kernel_launch(void* const* d_in, const int* in_sizes, int n_in,
                              void* d_out, int out_size, void* d_ws, size_t ws_size,
                              hipStream_t stream) {
    const float* x     = (const float*)d_in[0];
    const float* Wq    = (const float*)d_in[1];
    const float* bq    = (const float*)d_in[2];
    const float* Wk    = (const float*)d_in[3];
    const float* bk    = (const float*)d_in[4];
    const float* Wv    = (const float*)d_in[5];
    const float* bv    = (const float*)d_in[6];
    const float* gamma = (const float*)d_in[7];
    float* out = (float*)d_out;

    char* ws = (char*)d_ws;
    unsigned short* Qt = (unsigned short*)(ws);                 // 1 MB
    unsigned short* Kt = (unsigned short*)(ws + (1u << 20));    // 1 MB
    unsigned short* V  = (unsigned short*)(ws + (2u << 20));    // 8 MB
    unsigned short* Wb = (unsigned short*)(ws + (10u << 20));   // 160 KB

    wconv_kernel<<<dim3(80), 256, 0, stream>>>(Wq, Wk, Wv, Wb);
    proj_kernel<<<dim3(N_ / 32, B_), 256, 0, stream>>>(
        x, Wb, bq, bk, bv, Qt, Kt, V);
    attn_kernel<<<dim3(512), 512, 0, stream>>>(
        Qt, Kt, V, x, gamma, out);
}